// Round 1
// baseline (447.229 us; speedup 1.0000x reference)
//
#include <hip/hip_runtime.h>

// GraphSAGE 2-layer pipeline, fp32.
// N=50000 nodes, E=600000 edges. edge_index assumed int32 per harness doc
// ("integer -> const int*"). If output is garbage next round, switch to int64.

#define NN   50000
#define EE   600000
#define NBLK 49          // ceil(NN/1024)

// ---------------- CSR build ----------------

__global__ __launch_bounds__(256) void k_count(const int* __restrict__ ei,
                                               int* __restrict__ counts) {
    int e = blockIdx.x * 256 + threadIdx.x;
    if (e < EE) atomicAdd(&counts[ei[EE + e]], 1);
}

__global__ __launch_bounds__(256) void k_scan_a(const int* __restrict__ counts,
                                                int* __restrict__ bsums) {
    int b = blockIdx.x, t = threadIdx.x;
    int idx = b * 1024 + t * 4;
    int s = 0;
#pragma unroll
    for (int j = 0; j < 4; ++j)
        if (idx + j < NN) s += counts[idx + j];
#pragma unroll
    for (int off = 32; off > 0; off >>= 1) s += __shfl_down(s, off);
    __shared__ int ls[4];
    if ((t & 63) == 0) ls[t >> 6] = s;
    __syncthreads();
    if (t == 0) bsums[b] = ls[0] + ls[1] + ls[2] + ls[3];
}

__global__ void k_scan_b(int* __restrict__ bsums) {
    int t = threadIdx.x;                       // 64 threads
    int v = (t < NBLK) ? bsums[t] : 0;
    int orig = v;
#pragma unroll
    for (int off = 1; off < 64; off <<= 1) {
        int u = __shfl_up(v, off);
        if (t >= off) v += u;
    }
    if (t < NBLK) bsums[t] = v - orig;          // exclusive
}

__global__ __launch_bounds__(256) void k_scan_c(const int* __restrict__ counts,
                                                const int* __restrict__ bsums,
                                                int* __restrict__ rowp) {
    int b = blockIdx.x, t = threadIdx.x;
    int lane = t & 63, wave = t >> 6;
    int idx = b * 1024 + t * 4;
    int c[4], s = 0;
#pragma unroll
    for (int j = 0; j < 4; ++j) {
        c[j] = (idx + j < NN) ? counts[idx + j] : 0;
        s += c[j];
    }
    int sv = s;                                 // inclusive wave scan
#pragma unroll
    for (int off = 1; off < 64; off <<= 1) {
        int u = __shfl_up(sv, off);
        if (lane >= off) sv += u;
    }
    __shared__ int lsum[4];
    if (lane == 63) lsum[wave] = sv;
    __syncthreads();
    int woff = 0;
    for (int wv = 0; wv < wave; ++wv) woff += lsum[wv];
    int base = bsums[b] + woff + (sv - s);      // exclusive prefix for this thread
#pragma unroll
    for (int j = 0; j < 4; ++j) {
        if (idx + j < NN) { rowp[idx + j] = base; base += c[j]; }
    }
}

__global__ __launch_bounds__(256) void k_scatter(const int* __restrict__ ei,
                                                 const int* __restrict__ rowp,
                                                 int* __restrict__ cursor,
                                                 int* __restrict__ col) {
    int e = blockIdx.x * 256 + threadIdx.x;
    if (e < EE) {
        int d = ei[EE + e];
        int p = atomicAdd(&cursor[d], 1);
        col[rowp[d] + p] = ei[e];
    }
}

// ---------------- GEMM: h0 = x @ W_pre + b_pre  (K=256, M=128) ----------------
// 64-row blocks, 256 threads, each thread 8 rows x 4 cols. XOR-swizzled A tile.

__global__ __launch_bounds__(256) void k_gemm_pre(const float* __restrict__ x,
                                                  const float* __restrict__ Wp,
                                                  const float* __restrict__ bp,
                                                  float* __restrict__ h0) {
    __shared__ float xs[64 * 64];    // swizzled float4 chunks, row stride 64
    __shared__ float ws[64 * 128];
    const int t = threadIdx.x;
    const int row0 = blockIdx.x << 6;
    const int col4 = (t & 31) << 2;
    const int rg = t >> 5;           // 0..7

    float acc[8][4];
#pragma unroll
    for (int i = 0; i < 8; ++i)
#pragma unroll
        for (int j = 0; j < 4; ++j) acc[i][j] = 0.f;

    for (int k0 = 0; k0 < 256; k0 += 64) {
#pragma unroll
        for (int j = 0; j < 4; ++j) {            // stage x tile (64x64)
            int cid = t + (j << 8);
            int r = cid >> 4, c = cid & 15;
            int gr = row0 + r;
            float4 v = make_float4(0.f, 0.f, 0.f, 0.f);
            if (gr < NN) v = *(const float4*)&x[(size_t)gr * 256 + k0 + (c << 2)];
            int sc = c ^ (r >> 3);
            *(float4*)&xs[(r << 6) + (sc << 2)] = v;
        }
#pragma unroll
        for (int j = 0; j < 8; ++j) {            // stage W tile (64x128)
            int cid = t + (j << 8);
            int r = cid >> 5, c = cid & 31;
            *(float4*)&ws[(r << 7) + (c << 2)] =
                *(const float4*)&Wp[(size_t)(k0 + r) * 128 + (c << 2)];
        }
        __syncthreads();
#pragma unroll
        for (int c = 0; c < 16; ++c) {
            float4 a[8];
#pragma unroll
            for (int i = 0; i < 8; ++i) {
                int r = rg + (i << 3);           // r>>3 == i
                a[i] = *(const float4*)&xs[(r << 6) + ((c ^ i) << 2)];
            }
#pragma unroll
            for (int q = 0; q < 4; ++q) {
                float4 w4 = *(const float4*)&ws[((c << 2) + q) * 128 + col4];
#pragma unroll
                for (int i = 0; i < 8; ++i) {
                    float av = ((const float*)&a[i])[q];
                    acc[i][0] = fmaf(av, w4.x, acc[i][0]);
                    acc[i][1] = fmaf(av, w4.y, acc[i][1]);
                    acc[i][2] = fmaf(av, w4.z, acc[i][2]);
                    acc[i][3] = fmaf(av, w4.w, acc[i][3]);
                }
            }
        }
        __syncthreads();
    }
    float4 b4 = *(const float4*)&bp[col4];
#pragma unroll
    for (int i = 0; i < 8; ++i) {
        int gr = row0 + rg + (i << 3);
        if (gr < NN) {
            float4 o = make_float4(acc[i][0] + b4.x, acc[i][1] + b4.y,
                                   acc[i][2] + b4.z, acc[i][3] + b4.w);
            *(float4*)&h0[(size_t)gr * 128 + col4] = o;
        }
    }
}

// ---------------- Dual GEMM: T = A@W1, R = A@W2  (K=128, M in {128,64}) -------
// A tile staged once (in-place T=A per-block is safe: reads complete first).

template <int M, int RPT, int RG>
__device__ inline void dual_tile(const float* as, const float* ws, int k0,
                                 int rg, int col4, float (&acc)[RPT][4]) {
#pragma unroll
    for (int c = 0; c < 16; ++c) {
        int cg = (k0 >> 2) + c;
        float4 a[RPT];
#pragma unroll
        for (int i = 0; i < RPT; ++i) {
            int r = rg + RG * i;
            int sc = cg ^ (r >> 3);
            a[i] = *(const float4*)&as[(r << 7) + (sc << 2)];
        }
#pragma unroll
        for (int q = 0; q < 4; ++q) {
            float4 w4 = *(const float4*)&ws[((c << 2) + q) * M + col4];
#pragma unroll
            for (int i = 0; i < RPT; ++i) {
                float av = ((const float*)&a[i])[q];
                acc[i][0] = fmaf(av, w4.x, acc[i][0]);
                acc[i][1] = fmaf(av, w4.y, acc[i][1]);
                acc[i][2] = fmaf(av, w4.z, acc[i][2]);
                acc[i][3] = fmaf(av, w4.w, acc[i][3]);
            }
        }
    }
}

template <int M>
__global__ __launch_bounds__(256) void k_gemm_dual(const float* __restrict__ A,
                                                   const float* __restrict__ W1,
                                                   const float* __restrict__ W2,
                                                   float* __restrict__ T,
                                                   float* __restrict__ R) {
    constexpr int COLS4 = M >> 2;         // 32 or 16
    constexpr int RG = 256 / COLS4;       // 8 or 16
    constexpr int RPT = 64 / RG;          // 8 or 4
    __shared__ float as[64 * 128];
    __shared__ float ws[64 * M];
    const int t = threadIdx.x;
    const int row0 = blockIdx.x << 6;
    const int col4 = (t % COLS4) << 2;
    const int rg = t / COLS4;

#pragma unroll
    for (int j = 0; j < 8; ++j) {                  // stage full A tile 64x128
        int cid = t + (j << 8);
        int r = cid >> 5, c = cid & 31;
        int gr = row0 + r;
        float4 v = make_float4(0.f, 0.f, 0.f, 0.f);
        if (gr < NN) v = *(const float4*)&A[(size_t)gr * 128 + (c << 2)];
        int sc = c ^ (r >> 3);
        *(float4*)&as[(r << 7) + (sc << 2)] = v;
    }

    float accT[RPT][4], accR[RPT][4];
#pragma unroll
    for (int i = 0; i < RPT; ++i)
#pragma unroll
        for (int j = 0; j < 4; ++j) { accT[i][j] = 0.f; accR[i][j] = 0.f; }

    for (int k0 = 0; k0 < 128; k0 += 64) {
        __syncthreads();
#pragma unroll
        for (int j = 0; j < M / 16; ++j) {         // stage W1 chunk
            int cid = t + (j << 8);
            int r = cid / COLS4, c = cid % COLS4;
            *(float4*)&ws[r * M + (c << 2)] =
                *(const float4*)&W1[(size_t)(k0 + r) * M + (c << 2)];
        }
        __syncthreads();
        dual_tile<M, RPT, RG>(as, ws, k0, rg, col4, accT);
        __syncthreads();
#pragma unroll
        for (int j = 0; j < M / 16; ++j) {         // stage W2 chunk
            int cid = t + (j << 8);
            int r = cid / COLS4, c = cid % COLS4;
            *(float4*)&ws[r * M + (c << 2)] =
                *(const float4*)&W2[(size_t)(k0 + r) * M + (c << 2)];
        }
        __syncthreads();
        dual_tile<M, RPT, RG>(as, ws, k0, rg, col4, accR);
    }

#pragma unroll
    for (int i = 0; i < RPT; ++i) {
        int gr = row0 + rg + RG * i;
        if (gr < NN) {
            *(float4*)&T[(size_t)gr * M + col4] =
                make_float4(accT[i][0], accT[i][1], accT[i][2], accT[i][3]);
            *(float4*)&R[(size_t)gr * M + col4] =
                make_float4(accR[i][0], accR[i][1], accR[i][2], accR[i][3]);
        }
    }
}

// ---------------- Aggregation 1: h1 = relu(mean(t1[src]) + bl1 + r1) ----------
// one wave per node; 128 dims as float2/lane; writes h1 in-place into r1.

__global__ __launch_bounds__(256) void k_aggr1(const float* __restrict__ t1,
                                               float* __restrict__ r1,
                                               const int* __restrict__ rowp,
                                               const int* __restrict__ counts,
                                               const int* __restrict__ col,
                                               const float* __restrict__ bl1) {
    int node = blockIdx.x * 4 + (threadIdx.x >> 6);
    int lane = threadIdx.x & 63;
    if (node >= NN) return;
    int e0 = rowp[node], cnt = counts[node];
    float ax = 0.f, ay = 0.f;
    const float2* T = (const float2*)t1;
    for (int base = 0; base < cnt; base += 64) {
        int m = cnt - base; if (m > 64) m = 64;
        int myS = (base + lane < cnt) ? col[e0 + base + lane] : 0;
        for (int i = 0; i < m; ++i) {
            int s = __shfl(myS, i);
            float2 v = T[(size_t)s * 64 + lane];
            ax += v.x; ay += v.y;
        }
    }
    float di = (cnt > 0) ? 1.0f / (float)cnt : 0.0f;
    float2 r = ((const float2*)r1)[(size_t)node * 64 + lane];
    float2 bb = ((const float2*)bl1)[lane];
    float2 h;
    h.x = fmaxf(fmaf(ax, di, bb.x + r.x), 0.0f);
    h.y = fmaxf(fmaf(ay, di, bb.y + r.y), 0.0f);
    ((float2*)r1)[(size_t)node * 64 + lane] = h;
}

// ------- Aggregation 2 + L2 normalize: out = normalize(mean(t2[src]) + bl2 + r2)

__global__ __launch_bounds__(256) void k_aggr2(const float* __restrict__ t2,
                                               const float* __restrict__ r2,
                                               const int* __restrict__ rowp,
                                               const int* __restrict__ counts,
                                               const int* __restrict__ col,
                                               const float* __restrict__ bl2,
                                               float* __restrict__ out) {
    int node = blockIdx.x * 4 + (threadIdx.x >> 6);
    int lane = threadIdx.x & 63;
    if (node >= NN) return;
    int e0 = rowp[node], cnt = counts[node];
    float acc = 0.f;
    for (int base = 0; base < cnt; base += 64) {
        int m = cnt - base; if (m > 64) m = 64;
        int myS = (base + lane < cnt) ? col[e0 + base + lane] : 0;
        for (int i = 0; i < m; ++i) {
            int s = __shfl(myS, i);
            acc += t2[(size_t)s * 64 + lane];
        }
    }
    float di = (cnt > 0) ? 1.0f / (float)cnt : 0.0f;
    float v = fmaf(acc, di, bl2[lane] + r2[(size_t)node * 64 + lane]);
    float ss = v * v;
#pragma unroll
    for (int off = 32; off > 0; off >>= 1) ss += __shfl_xor(ss, off);
    float nrm = sqrtf(ss);
    out[(size_t)node * 64 + lane] = v / fmaxf(nrm, 1e-12f);
}

// ---------------- launch ----------------

extern "C" void kernel_launch(void* const* d_in, const int* in_sizes, int n_in,
                              void* d_out, int out_size, void* d_ws, size_t ws_size,
                              hipStream_t stream) {
    const float* x    = (const float*)d_in[0];
    const int*   ei   = (const int*)d_in[1];
    const float* Wpre = (const float*)d_in[2];
    const float* bpre = (const float*)d_in[3];
    const float* Wl1  = (const float*)d_in[4];
    const float* bl1  = (const float*)d_in[5];
    const float* Wr1  = (const float*)d_in[6];
    const float* Wl2  = (const float*)d_in[7];
    const float* bl2  = (const float*)d_in[8];
    const float* Wr2  = (const float*)d_in[9];
    float* out = (float*)d_out;

    char* w = (char*)d_ws;
    int* counts = (int*)w;  w += (size_t)NN * 4;
    int* cursor = (int*)w;  w += (size_t)NN * 4;
    int* rowp   = (int*)w;  w += (size_t)NN * 4;
    int* bsums  = (int*)w;  w += 256;
    int* col    = (int*)w;  w += (size_t)EE * 4;
    float* t1   = (float*)w; w += (size_t)NN * 128 * 4;   // h0, then t1 (in-place), 25.6MB
    float* r1   = (float*)w; w += (size_t)NN * 128 * 4;   // r1, then h1 (in-place)
    float* t2   = (float*)w; w += (size_t)NN * 64 * 4;
    float* r2   = (float*)w; w += (size_t)NN * 64 * 4;
    // total ws use ~79.8 MB

    hipMemsetAsync(counts, 0, (size_t)NN * 8, stream);    // counts + cursor

    dim3 b256(256);
    dim3 gE((EE + 255) / 256);
    k_count<<<gE, b256, 0, stream>>>(ei, counts);
    k_scan_a<<<dim3(NBLK), b256, 0, stream>>>(counts, bsums);
    k_scan_b<<<dim3(1), dim3(64), 0, stream>>>(bsums);
    k_scan_c<<<dim3(NBLK), b256, 0, stream>>>(counts, bsums, rowp);
    k_scatter<<<gE, b256, 0, stream>>>(ei, rowp, cursor, col);

    dim3 gG((NN + 63) / 64);
    k_gemm_pre<<<gG, b256, 0, stream>>>(x, Wpre, bpre, t1);            // h0 -> t1
    k_gemm_dual<128><<<gG, b256, 0, stream>>>(t1, Wl1, Wr1, t1, r1);   // t1,r1
    k_aggr1<<<dim3((NN + 3) / 4), b256, 0, stream>>>(t1, r1, rowp, counts, col, bl1); // h1 -> r1
    k_gemm_dual<64><<<gG, b256, 0, stream>>>(r1, Wl2, Wr2, t2, r2);    // t2,r2
    k_aggr2<<<dim3((NN + 3) / 4), b256, 0, stream>>>(t2, r2, rowp, counts, col, bl2, out);
}